// Round 4
// baseline (148.629 us; speedup 1.0000x reference)
//
#include <hip/hip_runtime.h>
#include <hip/hip_bf16.h>

// Problem constants
#define N_ROWS 8192
#define D_DIM  1024
#define HALF_N 4096
#define N_TILES 2080             // 64*65/2 upper-triangular 128x128 tile pairs
#define N_RED  8                 // parallel loss-reduction blocks
constexpr float INV_T = 1.0f / 0.07f;   // 14.2857143 — also the fixed softmax max M

typedef __attribute__((ext_vector_type(4)))  float f32x4;
typedef __attribute__((ext_vector_type(16))) float f32x16;
typedef __attribute__((ext_vector_type(4)))  int   i32x4;
typedef __attribute__((ext_vector_type(8)))  int   i32x8;

// async global->LDS, 16B/lane. LDS dest is wave-uniform base + lane*16.
__device__ __forceinline__ void async_ld16(const void* g, void* lds) {
    __builtin_amdgcn_global_load_lds(
        (const __attribute__((address_space(1))) void*)g,
        (__attribute__((address_space(3))) void*)lds,
        16, 0, 0);
}

// pack 4 floats -> 4 OCP e4m3 bytes in one dword
__device__ __forceinline__ unsigned int pk_fp8x4(float a, float b, float c, float d) {
    int v = __builtin_amdgcn_cvt_pk_fp8_f32(a, b, 0, false);   // bytes 0,1
    v = __builtin_amdgcn_cvt_pk_fp8_f32(c, d, v, true);        // bytes 2,3
    return (unsigned int)v;
}

// two b128 LDS reads -> one v8i32 MX fragment (32 fp8 bytes / lane)
__device__ __forceinline__ i32x8 ld_frag(const unsigned char* rowbase, int lo, int hi) {
    i32x4 L = *(const i32x4*)(rowbase + lo);
    i32x4 H = *(const i32x4*)(rowbase + hi);
    i32x8 r;
    r[0] = L[0]; r[1] = L[1]; r[2] = L[2]; r[3] = L[3];
    r[4] = H[0]; r[5] = H[1]; r[6] = H[2]; r[7] = H[3];
    return r;
}

// MX-scaled fp8 MFMA, scales fixed at e8m0 0x7F = 2^0 = 1.0 (exact fp8 product,
// 2x the non-scaled fp8 rate: 4686 vs 2047 TF ubench). fmtA=fmtB=0 (OCP e4m3).
#define MXMFMA(AF, BF, ACC) ACC = __builtin_amdgcn_mfma_scale_f32_32x32x64_f8f6f4( \
        AF, BF, ACC, 0, 0, 0, 0x7F7F7F7F, 0, 0x7F7F7F7F)

// ---------------------------------------------------------------------------
// Kernel 1: row norms + fp8 e4m3 normalized copy + zeroing of row_sum and the
// handshake cells. One wave per row. (unchanged — measured fine)
__global__ __launch_bounds__(256) void norm_kernel(const float* __restrict__ feat,
                                                   unsigned char* __restrict__ fn8,
                                                   float* __restrict__ row_sum,
                                                   unsigned int* __restrict__ done_cnt,
                                                   unsigned int* __restrict__ fin_cnt,
                                                   float* __restrict__ loss_acc) {
    const int w = threadIdx.x >> 6, lane = threadIdx.x & 63;
    const int row = blockIdx.x * 4 + w;
    if (blockIdx.x == 0 && threadIdx.x == 0) {
        *done_cnt = 0u;
        *fin_cnt = 0u;
        *loss_acc = 0.f;
    }
    const float4* src = (const float4*)(feat + (size_t)row * D_DIM);
    float4 v[4];
    float ss = 0.f;
#pragma unroll
    for (int t = 0; t < 4; ++t) {
        v[t] = src[lane + 64 * t];
        ss += v[t].x * v[t].x + v[t].y * v[t].y + v[t].z * v[t].z + v[t].w * v[t].w;
    }
#pragma unroll
    for (int off = 32; off; off >>= 1) ss += __shfl_xor(ss, off);
    float nrm = fmaxf(sqrtf(ss), 1e-8f);
    if (lane == 0) row_sum[row] = 0.f;
    const float inv = 1.0f / nrm;
    unsigned int* dst = (unsigned int*)(fn8 + (size_t)row * D_DIM);
#pragma unroll
    for (int t = 0; t < 4; ++t)
        dst[lane + 64 * t] = pk_fp8x4(v[t].x * inv, v[t].y * inv, v[t].z * inv, v[t].w * inv);
}

// ---------------------------------------------------------------------------
// Kernel 2 (r21 = r20 resubmit after infra failure): r16's proven 128x128 /
// 2-barrier / single-buffer skeleton, inner loop moved to MX-scaled fp8
// (mfma_scale_f32_32x32x64_f8f6f4, scales=1):
//  * same fp8 bytes, 2x MFMA rate — measured 1.64x on exactly this structure
//    (learn_hip m145->m148: 995 -> 1628 TF)
//  * BK=128 (8 K-steps, 16 barriers total vs 32), LDS 32 KB
//  * 8-unit XOR swizzle u_phys = u_log ^ (row&7): staged via per-lane
//    pre-swizzled global source (linear LDS dest), read back de-swizzled;
//    each 16B unit-slot is read by exactly 8 of 64 lanes = the 8-dword/bank
//    minimum for a wave64 b128 read — throughput-conflict-free
//  * fragment: lane = row (l&31), K-half (l>>5), 32 contiguous K bytes
//    (= exactly one e8m0 scale block); K-permutation shared by A and B
//  * 32x32 C/D layout epilogue: col=lane&31, row=(reg&3)+8*(reg>>2)+4*(l>>5)
//  * fence-free done-counter loss tail unchanged
__global__ __launch_bounds__(256) void simgemm_kernel(const unsigned char* __restrict__ fn8,
                                                      float* __restrict__ row_sum,
                                                      float* __restrict__ s_target,
                                                      unsigned int* __restrict__ done_cnt,
                                                      unsigned int* __restrict__ fin_cnt,
                                                      float* __restrict__ loss_acc,
                                                      float* __restrict__ out) {
    __shared__ __align__(16) unsigned char As[128 * 128];   // 16 KiB
    __shared__ __align__(16) unsigned char Bs[128 * 128];   // 16 KiB
    // triangular decode: t -> (I,J), I<=J
    const int t = blockIdx.x;
    int a = (int)((sqrtf(8.f * (float)t + 1.f) - 1.f) * 0.5f);
    while ((a + 1) * (a + 2) / 2 <= t) ++a;
    while (a * (a + 1) / 2 > t) --a;
    const int I = t - a * (a + 1) / 2;   // row-tile index (<= J)
    const int J = a;                     // col-tile index
    const int r0 = I * 128, c0 = J * 128;
    const bool isdiag = (I == J);
    const bool haspair = (J == I + 32);  // contains sim[i, i+4096] for rows in I

    const int tid = threadIdx.x;
    const int w = tid >> 6, lane = tid & 63;
    const int wr = (w >> 1) * 64;  // wave's row base within tile
    const int wc = (w & 1) * 64;   // wave's col base within tile

    // ---- staging addressing (wave w stages rows [w*32, w*32+32) of A and B) ----
    // dest (linear, HW adds lane*16): As/Bs + w*4096 + i*1024  (i = 0..3)
    //   -> lane writes row_in_chunk = i*8 + (lane>>3), phys unit = lane&7
    // src pre-swizzled: logical unit = phys ^ (row&7) = (lane&7) ^ (lane>>3)
    const int srow = lane >> 3;                               // 0..7
    const int slog = ((lane & 7) ^ srow) * 16;                // pre-swizzled byte off
    const unsigned char* pa = fn8 + (size_t)(r0 + w * 32 + srow) * D_DIM + slog;
    const unsigned char* pb = fn8 + (size_t)(c0 + w * 32 + srow) * D_DIM + slog;

    // ---- fragment addressing ----
    const int fr = lane & 31;      // row (A) / col (B) within 32-chunk
    const int h = lane >> 5;       // K-half owner
    const int fs = fr & 7;         // de-swizzle key
    const unsigned char* pA0 = &As[(((w >> 1) * 2 + 0) * 4096) + fr * 128];
    const unsigned char* pA1 = &As[(((w >> 1) * 2 + 1) * 4096) + fr * 128];
    const unsigned char* pB0 = &Bs[(((w & 1) * 2 + 0) * 4096) + fr * 128];
    const unsigned char* pB1 = &Bs[(((w & 1) * 2 + 1) * 4096) + fr * 128];

    f32x16 acc[2][2] = {};

    for (int kt = 0; kt < 8; ++kt) {
        __syncthreads();   // previous step's frag reads done before overwrite
#pragma unroll
        for (int i = 0; i < 4; ++i) {
            async_ld16(pa + (size_t)i * 8 * D_DIM, &As[w * 4096 + i * 1024]);
            async_ld16(pb + (size_t)i * 8 * D_DIM, &Bs[w * 4096 + i * 1024]);
        }
        pa += 128; pb += 128;
        __syncthreads();   // drains vmcnt(0): staging visible

#pragma unroll
        for (int k64 = 0; k64 < 2; ++k64) {
            const int lo = ((4 * k64 + 2 * h) ^ fs) * 16;
            const int hi = ((4 * k64 + 2 * h + 1) ^ fs) * 16;
            i32x8 a0 = ld_frag(pA0, lo, hi);
            i32x8 a1 = ld_frag(pA1, lo, hi);
            i32x8 b0 = ld_frag(pB0, lo, hi);
            i32x8 b1 = ld_frag(pB1, lo, hi);
            MXMFMA(a0, b0, acc[0][0]);
            MXMFMA(a0, b1, acc[0][1]);
            MXMFMA(a1, b0, acc[1][0]);
            MXMFMA(a1, b1, acc[1][1]);
        }
    }

    // ---- epilogue: e = exp(sim - M); rows-in-I sums + (I<J) cols-in-J sums ----
    // 32x32 C/D layout: col = c0 + wc + tj*32 + (lane&31),
    //                   row = r0 + wr + ti*32 + (reg&3) + 8*(reg>>2) + 4*h
    const int colL = lane & 31;
    float cs[2] = {0.f, 0.f};
#pragma unroll
    for (int ti = 0; ti < 2; ++ti) {
#pragma unroll
        for (int reg = 0; reg < 16; ++reg) {
            const int rowL = (reg & 3) + 8 * (reg >> 2) + 4 * h;
            const int grow = r0 + wr + ti * 32 + rowL;
            float s = 0.f;
#pragma unroll
            for (int tj = 0; tj < 2; ++tj) {
                const int gcol = c0 + wc + tj * 32 + colL;
                float sim = acc[ti][tj][reg] * INV_T;
                float e = __expf(sim - INV_T);
                if (isdiag && grow == gcol) e = 0.f;   // diagonal mask
                if (haspair && gcol == grow + HALF_N) {
                    __hip_atomic_store(&s_target[grow], sim, __ATOMIC_RELAXED,
                                       __HIP_MEMORY_SCOPE_AGENT);
                    __hip_atomic_store(&s_target[gcol], sim, __ATOMIC_RELAXED,
                                       __HIP_MEMORY_SCOPE_AGENT);
                }
                s += e;
                cs[tj] += e;
            }
            // row path: reduce across the 32 column-lanes of this h-group
            s += __shfl_xor(s, 1);
            s += __shfl_xor(s, 2);
            s += __shfl_xor(s, 4);
            s += __shfl_xor(s, 8);
            s += __shfl_xor(s, 16);
            if (colL == 0) atomicAdd(&row_sum[grow], s);
        }
    }
    if (!isdiag) {
        // col path: lane l holds 32 of the wave's 64 rows for its column;
        // pair with lane l^32 (other h) to complete, one atomic per column
#pragma unroll
        for (int tj = 0; tj < 2; ++tj) {
            float s = cs[tj] + __shfl_xor(cs[tj], 32);
            if (h == 0) atomicAdd(&row_sum[c0 + wc + tj * 32 + colL], s);
        }
    }

    // ---- fence-free fused loss tail, 8-way parallel ----
    __syncthreads();   // all waves' vmem drained (compiler emits vmcnt(0) here)
    __shared__ unsigned int my_ord;
    if (tid == 0)
        my_ord = __hip_atomic_fetch_add(done_cnt, 1u, __ATOMIC_RELAXED,
                                        __HIP_MEMORY_SCOPE_AGENT);
    __syncthreads();
    const unsigned int ord = my_ord;
    if (ord >= N_TILES - N_RED) {
        // wait until ALL 2080 blocks have signalled (their sums are in).
        if (tid == 0) {
            while (__hip_atomic_load(done_cnt, __ATOMIC_RELAXED,
                                     __HIP_MEMORY_SCOPE_AGENT) < N_TILES)
                __builtin_amdgcn_s_sleep(1);
        }
        __syncthreads();
        const int slice = (int)(ord - (N_TILES - N_RED));   // 0..7
        const int base_row = slice * (N_ROWS / N_RED) + tid * 4;
        float rv[4], sv[4];
#pragma unroll
        for (int u = 0; u < 4; ++u) {
            rv[u] = __hip_atomic_load(&row_sum[base_row + u], __ATOMIC_RELAXED,
                                      __HIP_MEMORY_SCOPE_AGENT);
            sv[u] = __hip_atomic_load(&s_target[base_row + u], __ATOMIC_RELAXED,
                                      __HIP_MEMORY_SCOPE_AGENT);
        }
        float local = 0.f;
#pragma unroll
        for (int u = 0; u < 4; ++u)
            local += __logf(rv[u]) - sv[u];
#pragma unroll
        for (int off = 32; off; off >>= 1) local += __shfl_xor(local, off);
        __shared__ float part[4];
        if ((tid & 63) == 0) part[tid >> 6] = local;
        __syncthreads();
        if (tid == 0) {
            float bsum = part[0] + part[1] + part[2] + part[3];
            __hip_atomic_fetch_add(loss_acc, bsum, __ATOMIC_RELAXED,
                                   __HIP_MEMORY_SCOPE_AGENT);
            unsigned int f = __hip_atomic_fetch_add(fin_cnt, 1u, __ATOMIC_ACQ_REL,
                                                    __HIP_MEMORY_SCOPE_AGENT);
            if (f == N_RED - 1) {
                float accv = __hip_atomic_load(loss_acc, __ATOMIC_RELAXED,
                                               __HIP_MEMORY_SCOPE_AGENT);
                out[0] = INV_T + accv * (1.0f / N_ROWS);
            }
        }
    }
}

// ---------------------------------------------------------------------------
extern "C" void kernel_launch(void* const* d_in, const int* in_sizes, int n_in,
                              void* d_out, int out_size, void* d_ws, size_t ws_size,
                              hipStream_t stream) {
    const float* feat = (const float*)d_in[0];
    float* out = (float*)d_out;
    char* ws = (char*)d_ws;

    unsigned char* fn8 = (unsigned char*)ws;                  // 8192*1024 fp8 = 8 MiB
    size_t off = (size_t)N_ROWS * D_DIM;
    float* row_sum = (float*)(ws + off);   off += N_ROWS * sizeof(float);
    float* s_target = (float*)(ws + off);  off += N_ROWS * sizeof(float);
    unsigned int* done_cnt = (unsigned int*)(ws + off);  off += sizeof(unsigned int);
    unsigned int* fin_cnt = (unsigned int*)(ws + off);   off += sizeof(unsigned int);
    float* loss_acc = (float*)(ws + off);

    norm_kernel<<<N_ROWS / 4, 256, 0, stream>>>(feat, fn8, row_sum, done_cnt, fin_cnt, loss_acc);
    simgemm_kernel<<<N_TILES, 256, 0, stream>>>(fn8, row_sum, s_target, done_cnt, fin_cnt, loss_acc, out);
}